// Round 2
// baseline (455.848 us; speedup 1.0000x reference)
//
#include <hip/hip_runtime.h>
#include <hip/hip_bf16.h>
#include <cstdint>

#define NV 8192
#define FIN 512
#define FOUT 256
#define KS 4
#define ALPHA_LRELU 0.2f

using bf16x8 = __attribute__((ext_vector_type(8))) short;
using f32x4  = __attribute__((ext_vector_type(4))) float;

static __device__ __forceinline__ float b2f(ushort u) {
  union { uint32_t u32; float f; } v; v.u32 = ((uint32_t)u) << 16; return v.f;
}
static __device__ __forceinline__ ushort f2b(float f) {
  union { float f; uint32_t u; } v; v.f = f;
  uint32_t r = (v.u + 0x7fffu + ((v.u >> 16) & 1u)) >> 16;
  return (ushort)r;
}
// swizzled element index of an 8-elem (16B) chunk start; tile row stride 64 elems (128B)
static __device__ __forceinline__ int swz(int row, int kchunk) {
  return (row << 6) + (((kchunk ^ (row & 7)) & 7) << 3);
}

// ---------------- prep A: h (f32) -> hB (bf16), vectorized ----------------
__global__ void k_prep_h(const float* __restrict__ h, ushort* __restrict__ hB) {
  int idx = blockIdx.x * 256 + threadIdx.x;        // 1M threads, 4 f32 each
  float4 v = ((const float4*)h)[idx];
  ushort4 o;
  o.x = f2b(v.x); o.y = f2b(v.y); o.z = f2b(v.z); o.w = f2b(v.w);
  ((ushort4*)hB)[idx] = o;
}

// ---------------- prep B: W [512][256] f32 -> WT [256][512] bf16 ----------------
__global__ void k_prep_w(const float* __restrict__ W, ushort* __restrict__ WT) {
  int t = blockIdx.x * 256 + threadIdx.x;          // 131072 threads
  int n = t >> 9, k = t & 511;
  WT[(size_t)n * FIN + k] = f2b(W[(size_t)k * FOUT + n]);
}

// ---------------- kernel 1: WhT[c][i] = (h@W)^T in bf16 ----------------
// BM=64, BN=64, BK=64; 256 thr (4 waves, 2x2); grid (128, 4)
__global__ __launch_bounds__(256, 4) void k_gemm1(
    const ushort* __restrict__ hB, const ushort* __restrict__ WT,
    ushort* __restrict__ WhT) {
  __shared__ __align__(16) ushort As[64 * 64];
  __shared__ __align__(16) ushort Ws[64 * 64];
  const int t = threadIdx.x;
  const int lane = t & 63;
  const int w = t >> 6;
  const int wm = w >> 1, wn = w & 1;
  const int i0 = blockIdx.x * 64;
  const int n0 = blockIdx.y * 64;

  f32x4 acc[2][2] = {};
  const int srow = t & 63, sseg = t >> 6;          // staging: 2 chunks each array

  for (int kt = 0; kt < FIN / 64; ++kt) {
    const int k0 = kt * 64;
    const uint4* gA = (const uint4*)(hB + (size_t)(i0 + srow) * FIN + k0 + sseg * 16);
    const uint4* gB = (const uint4*)(WT + (size_t)(n0 + srow) * FIN + k0 + sseg * 16);
#pragma unroll
    for (int m = 0; m < 2; ++m) {
      uint4 va = gA[m];
      *(uint4*)&As[swz(srow, sseg * 2 + m)] = va;
      uint4 vb = gB[m];
      *(uint4*)&Ws[swz(srow, sseg * 2 + m)] = vb;
    }
    __syncthreads();
#pragma unroll
    for (int kk = 0; kk < 2; ++kk) {
      const int kc = kk * 4 + (lane >> 4);
      bf16x8 af[2], bfv[2];
#pragma unroll
      for (int fi = 0; fi < 2; ++fi)
        af[fi] = *(const bf16x8*)&As[swz(wm * 32 + fi * 16 + (lane & 15), kc)];
#pragma unroll
      for (int fj = 0; fj < 2; ++fj)
        bfv[fj] = *(const bf16x8*)&Ws[swz(wn * 32 + fj * 16 + (lane & 15), kc)];
#pragma unroll
      for (int fi = 0; fi < 2; ++fi)
#pragma unroll
        for (int fj = 0; fj < 2; ++fj)
          acc[fi][fj] = __builtin_amdgcn_mfma_f32_16x16x32_bf16(af[fi], bfv[fj], acc[fi][fj], 0, 0, 0);
    }
    __syncthreads();
  }
  // write transposed: WhT[col][row], 4 consecutive rows per lane -> ushort4
#pragma unroll
  for (int fi = 0; fi < 2; ++fi) {
    const int row0 = i0 + wm * 32 + fi * 16 + ((lane >> 4) << 2);
#pragma unroll
    for (int fj = 0; fj < 2; ++fj) {
      const int col = n0 + wn * 32 + fj * 16 + (lane & 15);
      ushort4 o;
      o.x = f2b(acc[fi][fj][0]); o.y = f2b(acc[fi][fj][1]);
      o.z = f2b(acc[fi][fj][2]); o.w = f2b(acc[fi][fj][3]);
      *(ushort4*)&WhT[(size_t)col * NV + row0] = o;
    }
  }
}

// ---------------- kernel 2: f1, f2, per-block max of f2 ----------------
__global__ void k_f12(const ushort* __restrict__ WhT, const float* __restrict__ a,
                      float* __restrict__ f1, float* __restrict__ f2,
                      float* __restrict__ f2bmax) {
  __shared__ float a1s[256], a2s[256];
  __shared__ float red[256];
  const int tid = threadIdx.x;
  a1s[tid] = a[tid];
  a2s[tid] = a[256 + tid];
  __syncthreads();
  const int i = blockIdx.x * 256 + tid;
  float s1 = 0.f, s2 = 0.f;
  for (int c = 0; c < 256; ++c) {
    float v = b2f(WhT[(size_t)c * NV + i]);
    s1 = fmaf(v, a1s[c], s1);
    s2 = fmaf(v, a2s[c], s2);
  }
  f1[i] = s1; f2[i] = s2;
  red[tid] = s2; __syncthreads();
  for (int off = 128; off > 0; off >>= 1) {
    if (tid < off) red[tid] = fmaxf(red[tid], red[tid + off]);
    __syncthreads();
  }
  if (tid == 0) f2bmax[blockIdx.x] = red[0];
}

// ---------------- kernel 3: fused mask/exp/PV partial GEMM ----------------
// BM=64 rows, BN=256 (full), K-split=4; 512 thr (8 waves, 2x4); grid 512
__global__ __launch_bounds__(512, 4) void k_gemm2(
    const int* __restrict__ adj, const ushort* __restrict__ WhT,
    const float* __restrict__ f1, const float* __restrict__ f2,
    const float* __restrict__ f2bmax,
    float* __restrict__ accP, float* __restrict__ Sp) {
  __shared__ __align__(16) ushort Ps[64 * 64];     // P tile (bf16 weights)
  __shared__ __align__(16) ushort Bs[256 * 64];    // WhT tile
  __shared__ float f2s[NV / KS];
  __shared__ float f1s[64], cs[64];

  const int t = threadIdx.x;
  const int lane = t & 63;
  const int w = t >> 6;
  const int wm = w >> 2, wn = w & 3;
  const int bid = blockIdx.x;
  const int ks = bid & (KS - 1);
  const int rb = bid >> 2;
  const int i0 = rb * 64;
  const int jbase = ks * (NV / KS);
  const int NT = (NV / KS) / 64;                   // 32 k-tiles

  float mf = -1e30f;
#pragma unroll
  for (int c = 0; c < 32; ++c) mf = fmaxf(mf, f2bmax[c]);
  if (t < 64) {
    float v = f1[i0 + t];
    f1s[t] = v;
    float e = v + mf;
    cs[t] = fmaxf(e, ALPHA_LRELU * e);             // c_i >= row max of e
  }
  for (int idx = t; idx < NV / KS; idx += 512) f2s[idx] = f2[jbase + idx];
  __syncthreads();

  const int pr = t >> 3, pq = t & 7;               // P stage: row 0..63, chunk 0..7
  const int bc = t & 255, bseg = t >> 8;           // B stage: col row 0..255, half
  const float f1r = f1s[pr], cr = cs[pr];
  float ssum = 0.f;
  f32x4 acc[2][4] = {};

  for (int kt = 0; kt < NT; ++kt) {
    const int j0 = jbase + kt * 64;
    // stage P: adj -> bf16 weights
    {
      const int4* ga = (const int4*)(adj + (size_t)(i0 + pr) * NV + j0 + pq * 8);
      int4 a0 = ga[0], a1 = ga[1];
      int av[8] = {a0.x, a0.y, a0.z, a0.w, a1.x, a1.y, a1.z, a1.w};
      const float* fz = &f2s[kt * 64 + pq * 8];
      ushort ub[8];
#pragma unroll
      for (int e = 0; e < 8; ++e) {
        float x = f1r + fz[e];
        float ee = fmaxf(x, ALPHA_LRELU * x) - cr;
        float wvv = (av[e] > 0) ? __expf(ee) : 0.f;
        ub[e] = f2b(wvv);
        ssum += b2f(ub[e]);                        // denom from rounded weights
      }
      uint4 pk;
      pk.x = (uint32_t)ub[0] | ((uint32_t)ub[1] << 16);
      pk.y = (uint32_t)ub[2] | ((uint32_t)ub[3] << 16);
      pk.z = (uint32_t)ub[4] | ((uint32_t)ub[5] << 16);
      pk.w = (uint32_t)ub[6] | ((uint32_t)ub[7] << 16);
      *(uint4*)&Ps[swz(pr, pq)] = pk;
    }
    // stage B: WhT tile rows (contiguous k)
    {
      const uint4* gb = (const uint4*)(WhT + (size_t)bc * NV + j0 + bseg * 32);
#pragma unroll
      for (int m = 0; m < 4; ++m) {
        uint4 v = gb[m];
        *(uint4*)&Bs[swz(bc, bseg * 4 + m)] = v;
      }
    }
    __syncthreads();
#pragma unroll
    for (int kk = 0; kk < 2; ++kk) {
      const int kc = kk * 4 + (lane >> 4);
      bf16x8 af[2], bfv[4];
#pragma unroll
      for (int fi = 0; fi < 2; ++fi)
        af[fi] = *(const bf16x8*)&Ps[swz(wm * 32 + fi * 16 + (lane & 15), kc)];
#pragma unroll
      for (int fj = 0; fj < 4; ++fj)
        bfv[fj] = *(const bf16x8*)&Bs[swz(wn * 64 + fj * 16 + (lane & 15), kc)];
#pragma unroll
      for (int fi = 0; fi < 2; ++fi)
#pragma unroll
        for (int fj = 0; fj < 4; ++fj)
          acc[fi][fj] = __builtin_amdgcn_mfma_f32_16x16x32_bf16(af[fi], bfv[fj], acc[fi][fj], 0, 0, 0);
    }
    __syncthreads();
  }

  // denom partial: reduce over 8 chunk-lanes of each row
  ssum += __shfl_xor(ssum, 1);
  ssum += __shfl_xor(ssum, 2);
  ssum += __shfl_xor(ssum, 4);
  if (pq == 0) Sp[(size_t)ks * NV + i0 + pr] = ssum;

  float* ab = accP + (size_t)ks * NV * FOUT;
#pragma unroll
  for (int fi = 0; fi < 2; ++fi) {
    const int ig = i0 + wm * 32 + fi * 16 + ((lane >> 4) << 2);
#pragma unroll
    for (int fj = 0; fj < 4; ++fj) {
      const int col = wn * 64 + fj * 16 + (lane & 15);
#pragma unroll
      for (int rr = 0; rr < 4; ++rr)
        ab[(size_t)(ig + rr) * FOUT + col] = acc[fi][fj][rr];
    }
  }
}

// ---------------- kernel 4: combine partials, divide, ELU, f32 out ----------------
__global__ void k_combine(const float* __restrict__ accP, const float* __restrict__ Sp,
                          float* __restrict__ out) {
  const size_t NF = (size_t)NV * FOUT;
  int g = blockIdx.x * 256 + threadIdx.x;          // 524288 groups of 4
  int i = g >> 6;
  float4 v0 = ((const float4*)accP)[g];
  float4 v1 = ((const float4*)(accP + NF))[g];
  float4 v2 = ((const float4*)(accP + 2 * NF))[g];
  float4 v3 = ((const float4*)(accP + 3 * NF))[g];
  float s = Sp[i] + Sp[NV + i] + Sp[2 * NV + i] + Sp[3 * NV + i];
  float inv = (s != 0.f) ? (1.0f / s) : 0.f;
  float xs0 = (v0.x + v1.x + v2.x + v3.x) * inv;
  float xs1 = (v0.y + v1.y + v2.y + v3.y) * inv;
  float xs2 = (v0.z + v1.z + v2.z + v3.z) * inv;
  float xs3 = (v0.w + v1.w + v2.w + v3.w) * inv;
  float4 o;
  o.x = xs0 > 0.f ? xs0 : expm1f(xs0);
  o.y = xs1 > 0.f ? xs1 : expm1f(xs1);
  o.z = xs2 > 0.f ? xs2 : expm1f(xs2);
  o.w = xs3 > 0.f ? xs3 : expm1f(xs3);
  ((float4*)out)[g] = o;
}

extern "C" void kernel_launch(void* const* d_in, const int* in_sizes, int n_in,
                              void* d_out, int out_size, void* d_ws, size_t ws_size,
                              hipStream_t stream) {
  const float* h   = (const float*)d_in[0];        // f32 [8192][512]
  const int*   adj = (const int*)d_in[1];          // int32 [8192][8192]
  const float* W   = (const float*)d_in[2];        // f32 [512][256]
  const float* a   = (const float*)d_in[3];        // f32 [512]
  float* out = (float*)d_out;                      // f32 [8192][256]

  char* ws = (char*)d_ws;
  ushort* hB   = (ushort*)ws;                                  // 8 MB
  ushort* WT   = (ushort*)(ws + (8ull << 20));                 // 256 KB
  ushort* WhT  = (ushort*)(ws + (8ull << 20) + (256ull << 10)); // 4 MB
  float*  f1   = (float*)(ws + (12ull << 20) + (256ull << 10));
  float*  f2   = f1 + NV;
  float*  f2bm = f2 + NV;                                      // 64 floats
  float*  Sp   = f2bm + 64;                                    // 4*8192 floats
  float*  accP = Sp + (size_t)KS * NV;                         // 4*8192*256 floats (32 MB)

  k_prep_h<<<(NV * FIN / 4) / 256, 256, 0, stream>>>(h, hB);
  k_prep_w<<<(FIN * FOUT) / 256, 256, 0, stream>>>(W, WT);
  k_gemm1<<<dim3(NV / 64, FOUT / 64), 256, 0, stream>>>(hB, WT, WhT);
  k_f12<<<NV / 256, 256, 0, stream>>>(WhT, a, f1, f2, f2bm);
  k_gemm2<<<(NV / 64) * KS, 512, 0, stream>>>(adj, WhT, f1, f2, f2bm, accP, Sp);
  k_combine<<<(NV * FOUT / 4) / 256, 256, 0, stream>>>(accP, Sp, out);
}

// Round 3
// 435.174 us; speedup vs baseline: 1.0475x; 1.0475x over previous
//
#include <hip/hip_runtime.h>
#include <hip/hip_bf16.h>
#include <cstdint>

#define NV 8192
#define FIN 512
#define FOUT 256
#define KS 4
#define ALPHA_LRELU 0.2f

using bf16x8 = __attribute__((ext_vector_type(8))) short;
using f32x4  = __attribute__((ext_vector_type(4))) float;

static __device__ __forceinline__ float b2f(ushort u) {
  union { uint32_t u32; float f; } v; v.u32 = ((uint32_t)u) << 16; return v.f;
}
static __device__ __forceinline__ ushort f2b(float f) {
  union { float f; uint32_t u; } v; v.f = f;
  uint32_t r = (v.u + 0x7fffu + ((v.u >> 16) & 1u)) >> 16;
  return (ushort)r;
}
// swizzled element index of an 8-elem (16B) chunk; tile row stride 64 elems (128B)
static __device__ __forceinline__ int swz(int row, int kchunk) {
  return (row << 6) + (((kchunk ^ (row & 7)) & 7) << 3);
}
// direct global->LDS, 16B per lane (dest = wave-uniform base + lane*16)
static __device__ __forceinline__ void gl_lds16(const ushort* g, ushort* l) {
  __builtin_amdgcn_global_load_lds(
      (const __attribute__((address_space(1))) uint32_t*)(uintptr_t)g,
      (__attribute__((address_space(3))) uint32_t*)(uint32_t)(uintptr_t)l,
      16, 0, 0);
}

// ---------------- prep A: h (f32) -> hB (bf16) ----------------
__global__ void k_prep_h(const float* __restrict__ h, ushort* __restrict__ hB) {
  int idx = blockIdx.x * 256 + threadIdx.x;
  float4 v = ((const float4*)h)[idx];
  ushort4 o;
  o.x = f2b(v.x); o.y = f2b(v.y); o.z = f2b(v.z); o.w = f2b(v.w);
  ((ushort4*)hB)[idx] = o;
}

// ---------------- prep B: W [512][256] f32 -> WT [256][512] bf16 ----------------
__global__ void k_prep_w(const float* __restrict__ W, ushort* __restrict__ WT) {
  int t = blockIdx.x * 256 + threadIdx.x;
  int n = t >> 9, k = t & 511;
  WT[(size_t)n * FIN + k] = f2b(W[(size_t)k * FOUT + n]);
}

// ---------------- kernel 1: WhT[c][i] = (h@W)^T in bf16 ----------------
__global__ __launch_bounds__(256, 4) void k_gemm1(
    const ushort* __restrict__ hB, const ushort* __restrict__ WT,
    ushort* __restrict__ WhT) {
  __shared__ __align__(16) ushort As[64 * 64];
  __shared__ __align__(16) ushort Ws[64 * 64];
  const int t = threadIdx.x;
  const int lane = t & 63;
  const int w = t >> 6;
  const int wm = w >> 1, wn = w & 1;
  const int i0 = blockIdx.x * 64;
  const int n0 = blockIdx.y * 64;

  f32x4 acc[2][2] = {};
  const int srow = t & 63, sseg = t >> 6;

  for (int kt = 0; kt < FIN / 64; ++kt) {
    const int k0 = kt * 64;
    const uint4* gA = (const uint4*)(hB + (size_t)(i0 + srow) * FIN + k0 + sseg * 16);
    const uint4* gB = (const uint4*)(WT + (size_t)(n0 + srow) * FIN + k0 + sseg * 16);
#pragma unroll
    for (int m = 0; m < 2; ++m) {
      uint4 va = gA[m];
      *(uint4*)&As[swz(srow, sseg * 2 + m)] = va;
      uint4 vb = gB[m];
      *(uint4*)&Ws[swz(srow, sseg * 2 + m)] = vb;
    }
    __syncthreads();
#pragma unroll
    for (int kk = 0; kk < 2; ++kk) {
      const int kc = kk * 4 + (lane >> 4);
      bf16x8 af[2], bfv[2];
#pragma unroll
      for (int fi = 0; fi < 2; ++fi)
        af[fi] = *(const bf16x8*)&As[swz(wm * 32 + fi * 16 + (lane & 15), kc)];
#pragma unroll
      for (int fj = 0; fj < 2; ++fj)
        bfv[fj] = *(const bf16x8*)&Ws[swz(wn * 32 + fj * 16 + (lane & 15), kc)];
#pragma unroll
      for (int fi = 0; fi < 2; ++fi)
#pragma unroll
        for (int fj = 0; fj < 2; ++fj)
          acc[fi][fj] = __builtin_amdgcn_mfma_f32_16x16x32_bf16(af[fi], bfv[fj], acc[fi][fj], 0, 0, 0);
    }
    __syncthreads();
  }
#pragma unroll
  for (int fi = 0; fi < 2; ++fi) {
    const int row0 = i0 + wm * 32 + fi * 16 + ((lane >> 4) << 2);
#pragma unroll
    for (int fj = 0; fj < 2; ++fj) {
      const int col = n0 + wn * 32 + fj * 16 + (lane & 15);
      ushort4 o;
      o.x = f2b(acc[fi][fj][0]); o.y = f2b(acc[fi][fj][1]);
      o.z = f2b(acc[fi][fj][2]); o.w = f2b(acc[fi][fj][3]);
      *(ushort4*)&WhT[(size_t)col * NV + row0] = o;
    }
  }
}

// ---------------- kernel 2: f1, f2, per-block (64-row) max of f2 ----------------
// grid 128, block 256 (4 waves); wave ws sums c in [ws*64, ws*64+64)
__global__ void k_f12(const ushort* __restrict__ WhT, const float* __restrict__ a,
                      float* __restrict__ f1, float* __restrict__ f2,
                      float* __restrict__ f2bmax) {
  __shared__ float a1s[256], a2s[256];
  __shared__ float r1[4][64], r2[4][64];
  const int tid = threadIdx.x;
  a1s[tid] = a[tid];
  a2s[tid] = a[256 + tid];
  const int ws = tid >> 6, ln = tid & 63;
  const int i = blockIdx.x * 64 + ln;
  __syncthreads();
  float s1 = 0.f, s2 = 0.f;
#pragma unroll 8
  for (int c = ws * 64; c < ws * 64 + 64; ++c) {
    float v = b2f(WhT[(size_t)c * NV + i]);
    s1 = fmaf(v, a1s[c], s1);
    s2 = fmaf(v, a2s[c], s2);
  }
  r1[ws][ln] = s1; r2[ws][ln] = s2;
  __syncthreads();
  if (ws == 0) {
    s1 = r1[0][ln] + r1[1][ln] + r1[2][ln] + r1[3][ln];
    s2 = r2[0][ln] + r2[1][ln] + r2[2][ln] + r2[3][ln];
    f1[i] = s1; f2[i] = s2;
    float m = s2;
#pragma unroll
    for (int off = 32; off > 0; off >>= 1) m = fmaxf(m, __shfl_xor(m, off));
    if (ln == 0) f2bmax[blockIdx.x] = m;
  }
}

// ---------------- kernel 2b: global max of f2 ----------------
__global__ void k_fmax(const float* __restrict__ f2bmax, float* __restrict__ mfp) {
  __shared__ float red[128];
  const int tid = threadIdx.x;
  red[tid] = f2bmax[tid];
  __syncthreads();
  for (int off = 64; off > 0; off >>= 1) {
    if (tid < off) red[tid] = fmaxf(red[tid], red[tid + off]);
    __syncthreads();
  }
  if (tid == 0) mfp[0] = red[0];
}

// ---------------- kernel 3: fused mask/exp/PV partial GEMM, 2-phase dbuf ----------------
// BM=64, BN=256 (full), K-split=4; 512 thr (8 waves, 2x4); grid 512
__global__ __launch_bounds__(512, 2) void k_gemm2(
    const int* __restrict__ adj, const ushort* __restrict__ WhT,
    const float* __restrict__ f1, const float* __restrict__ f2,
    const float* __restrict__ mfp,
    float* __restrict__ accP, float* __restrict__ Sp) {
  __shared__ __align__(16) ushort Ps[2][64 * 64];     // 16 KB
  __shared__ __align__(16) ushort Bs[2][256 * 64];    // 64 KB

  const int t = threadIdx.x;
  const int lane = t & 63;
  const int w = t >> 6;
  const int wm = w >> 2, wn = w & 3;
  const int bid = blockIdx.x;
  const int ks = bid & (KS - 1);
  const int rb = bid >> 2;
  const int i0 = rb * 64;
  const int jbase = ks * (NV / KS);
  const int NT = (NV / KS) / 64;                       // 32 k-tiles

  // P staging role: row pr (0..63), chunk pq (0..7)
  const int pr = t >> 3, pq = t & 7;
  const float mf = mfp[0];
  const float f1r = f1[i0 + pr];
  const float e0 = f1r + mf;
  const float cr = fmaxf(e0, ALPHA_LRELU * e0);        // c_i >= row max of e

  // B staging via gl_lds: lane -> (row, pre-swizzled chunk); linear LDS == swz tile
  const int lrow = lane >> 3;
  const int lchunk = (lane & 7) ^ lrow;
  const ushort* wsrc0 = WhT + (size_t)(w * 32 + lrow) * NV + jbase + lchunk * 8;
  const int* adjp = adj + (size_t)(i0 + pr) * NV + jbase + pq * 8;
  const float* f2p = f2 + jbase + pq * 8;

  float ssum = 0.f;
  f32x4 acc[2][4] = {};
  int av[8]; float fz[8];

  auto stage_load = [&](int koff, int buf) {
#pragma unroll
    for (int q = 0; q < 4; ++q)
      gl_lds16(wsrc0 + (size_t)q * 8 * NV + koff, &Bs[buf][(w * 4 + q) * 512]);
    int4 a0 = *(const int4*)(adjp + koff);
    int4 a1 = *(const int4*)(adjp + koff + 4);
    float4 z0 = *(const float4*)(f2p + koff);
    float4 z1 = *(const float4*)(f2p + koff + 4);
    av[0] = a0.x; av[1] = a0.y; av[2] = a0.z; av[3] = a0.w;
    av[4] = a1.x; av[5] = a1.y; av[6] = a1.z; av[7] = a1.w;
    fz[0] = z0.x; fz[1] = z0.y; fz[2] = z0.z; fz[3] = z0.w;
    fz[4] = z1.x; fz[5] = z1.y; fz[6] = z1.z; fz[7] = z1.w;
  };
  auto stage_finish = [&](int buf) {
    ushort ub[8];
#pragma unroll
    for (int e = 0; e < 8; ++e) {
      float x = f1r + fz[e];
      float ee = fmaxf(x, ALPHA_LRELU * x) - cr;
      float wv = (av[e] > 0) ? __expf(ee) : 0.f;
      ub[e] = f2b(wv);
      ssum += b2f(ub[e]);
    }
    uint4 pk;
    pk.x = (uint32_t)ub[0] | ((uint32_t)ub[1] << 16);
    pk.y = (uint32_t)ub[2] | ((uint32_t)ub[3] << 16);
    pk.z = (uint32_t)ub[4] | ((uint32_t)ub[5] << 16);
    pk.w = (uint32_t)ub[6] | ((uint32_t)ub[7] << 16);
    *(uint4*)&Ps[buf][swz(pr, pq)] = pk;
  };

  // prologue: stage tile 0 into buf 0
  stage_load(0, 0);
  stage_finish(0);
  __syncthreads();

  int cur = 0;
  for (int kt = 0; kt < NT; ++kt) {
    const bool pf = (kt + 1 < NT);
    if (pf) stage_load((kt + 1) * 64, cur ^ 1);        // async loads in flight
    // compute current tile
#pragma unroll
    for (int kk = 0; kk < 2; ++kk) {
      const int kc = kk * 4 + (lane >> 4);
      bf16x8 af[2], bfv[4];
#pragma unroll
      for (int fi = 0; fi < 2; ++fi)
        af[fi] = *(const bf16x8*)&Ps[cur][swz(wm * 32 + fi * 16 + (lane & 15), kc)];
#pragma unroll
      for (int fj = 0; fj < 4; ++fj)
        bfv[fj] = *(const bf16x8*)&Bs[cur][swz(wn * 64 + fj * 16 + (lane & 15), kc)];
#pragma unroll
      for (int fi = 0; fi < 2; ++fi)
#pragma unroll
        for (int fj = 0; fj < 4; ++fj)
          acc[fi][fj] = __builtin_amdgcn_mfma_f32_16x16x32_bf16(af[fi], bfv[fj], acc[fi][fj], 0, 0, 0);
    }
    if (pf) stage_finish(cur ^ 1);                     // exp + ds_write after MFMA
    __syncthreads();                                   // drains vmcnt+lgkm (one per tile)
    cur ^= 1;
  }

  // denom partial: reduce over the 8 chunk-lanes of each row
  ssum += __shfl_xor(ssum, 1);
  ssum += __shfl_xor(ssum, 2);
  ssum += __shfl_xor(ssum, 4);
  if (pq == 0) Sp[(size_t)ks * NV + i0 + pr] = ssum;

  float* ab = accP + (size_t)ks * NV * FOUT;
#pragma unroll
  for (int fi = 0; fi < 2; ++fi) {
    const int ig = i0 + wm * 32 + fi * 16 + ((lane >> 4) << 2);
#pragma unroll
    for (int fj = 0; fj < 4; ++fj) {
      const int col = wn * 64 + fj * 16 + (lane & 15);
#pragma unroll
      for (int rr = 0; rr < 4; ++rr)
        ab[(size_t)(ig + rr) * FOUT + col] = acc[fi][fj][rr];
    }
  }
}

// ---------------- kernel 4: combine partials, divide, ELU, f32 out ----------------
__global__ void k_combine(const float* __restrict__ accP, const float* __restrict__ Sp,
                          float* __restrict__ out) {
  const size_t NF = (size_t)NV * FOUT;
  int g = blockIdx.x * 256 + threadIdx.x;
  int i = g >> 6;
  float4 v0 = ((const float4*)accP)[g];
  float4 v1 = ((const float4*)(accP + NF))[g];
  float4 v2 = ((const float4*)(accP + 2 * NF))[g];
  float4 v3 = ((const float4*)(accP + 3 * NF))[g];
  float s = Sp[i] + Sp[NV + i] + Sp[2 * NV + i] + Sp[3 * NV + i];
  float inv = (s != 0.f) ? (1.0f / s) : 0.f;
  float xs0 = (v0.x + v1.x + v2.x + v3.x) * inv;
  float xs1 = (v0.y + v1.y + v2.y + v3.y) * inv;
  float xs2 = (v0.z + v1.z + v2.z + v3.z) * inv;
  float xs3 = (v0.w + v1.w + v2.w + v3.w) * inv;
  float4 o;
  o.x = xs0 > 0.f ? xs0 : expm1f(xs0);
  o.y = xs1 > 0.f ? xs1 : expm1f(xs1);
  o.z = xs2 > 0.f ? xs2 : expm1f(xs2);
  o.w = xs3 > 0.f ? xs3 : expm1f(xs3);
  ((float4*)out)[g] = o;
}

extern "C" void kernel_launch(void* const* d_in, const int* in_sizes, int n_in,
                              void* d_out, int out_size, void* d_ws, size_t ws_size,
                              hipStream_t stream) {
  const float* h   = (const float*)d_in[0];        // f32 [8192][512]
  const int*   adj = (const int*)d_in[1];          // int32 [8192][8192]
  const float* W   = (const float*)d_in[2];        // f32 [512][256]
  const float* a   = (const float*)d_in[3];        // f32 [512]
  float* out = (float*)d_out;                      // f32 [8192][256]

  char* ws = (char*)d_ws;
  ushort* hB   = (ushort*)ws;                                   // 8 MB
  ushort* WT   = (ushort*)(ws + (8ull << 20));                  // 256 KB
  ushort* WhT  = (ushort*)(ws + (8ull << 20) + (256ull << 10)); // 4 MB
  float*  f1   = (float*)(ws + (12ull << 20) + (256ull << 10));
  float*  f2   = f1 + NV;
  float*  f2bm = f2 + NV;                                       // 128 floats
  float*  mfp  = f2bm + 128;                                    // 1 float (pad 64)
  float*  Sp   = mfp + 64;                                      // 4*8192 floats
  float*  accP = Sp + (size_t)KS * NV;                          // 32 MB

  k_prep_h<<<(NV * FIN / 4) / 256, 256, 0, stream>>>(h, hB);
  k_prep_w<<<(FIN * FOUT) / 256, 256, 0, stream>>>(W, WT);
  k_gemm1<<<dim3(NV / 64, FOUT / 64), 256, 0, stream>>>(hB, WT, WhT);
  k_f12<<<NV / 64, 256, 0, stream>>>(WhT, a, f1, f2, f2bm);
  k_fmax<<<1, 128, 0, stream>>>(f2bm, mfp);
  k_gemm2<<<(NV / 64) * KS, 512, 0, stream>>>(adj, WhT, f1, f2, mfp, accP, Sp);
  k_combine<<<(NV * FOUT / 4) / 256, 256, 0, stream>>>(accP, Sp, out);
}

// Round 4
// 430.631 us; speedup vs baseline: 1.0586x; 1.0105x over previous
//
#include <hip/hip_runtime.h>
#include <hip/hip_bf16.h>
#include <cstdint>

#define NV 8192
#define FIN 512
#define FOUT 256
#define KS 4
#define ALPHA_LRELU 0.2f

using bf16x8 = __attribute__((ext_vector_type(8))) short;
using f32x4  = __attribute__((ext_vector_type(4))) float;

static __device__ __forceinline__ float b2f(ushort u) {
  union { uint32_t u32; float f; } v; v.u32 = ((uint32_t)u) << 16; return v.f;
}
static __device__ __forceinline__ ushort f2b(float f) {
  union { float f; uint32_t u; } v; v.f = f;
  uint32_t r = (v.u + 0x7fffu + ((v.u >> 16) & 1u)) >> 16;
  return (ushort)r;
}
static __device__ __forceinline__ uint32_t pk2(float a, float b) {
  return (uint32_t)f2b(a) | ((uint32_t)f2b(b) << 16);
}
// swizzled element index of an 8-elem (16B) chunk; tile row stride 64 elems (128B)
static __device__ __forceinline__ int swz(int row, int kchunk) {
  return (row << 6) + (((kchunk ^ (row & 7)) & 7) << 3);
}
// direct global->LDS, 16B per lane (dest = wave-uniform base + lane*16)
static __device__ __forceinline__ void gl_lds16(const ushort* g, ushort* l) {
  __builtin_amdgcn_global_load_lds(
      (const __attribute__((address_space(1))) uint32_t*)(uintptr_t)g,
      (__attribute__((address_space(3))) uint32_t*)(uint32_t)(uintptr_t)l,
      16, 0, 0);
}

// ---------------- prep: W [512][256] f32 -> WT [256][512] bf16 ----------------
__global__ void k_prep_w(const float* __restrict__ W, ushort* __restrict__ WT) {
  int t = blockIdx.x * 256 + threadIdx.x;
  int n = t >> 9, k = t & 511;
  WT[(size_t)n * FIN + k] = f2b(W[(size_t)k * FOUT + n]);
}

// ---------------- kernel 1: WhT[c][i] = (h@W)^T bf16, + f1/f2 partials ----------------
// BM=64, BN=64, BK=64; 256 thr (4 waves, 2x2); grid (128, 4)
__global__ __launch_bounds__(256, 4) void k_gemm1(
    const float* __restrict__ h, const ushort* __restrict__ WT,
    const float* __restrict__ a,
    ushort* __restrict__ WhT, float* __restrict__ f1, float* __restrict__ f2) {
  __shared__ __align__(16) ushort As[64 * 64];
  __shared__ __align__(16) ushort Ws[64 * 64];
  const int t = threadIdx.x;
  const int lane = t & 63;
  const int w = t >> 6;
  const int wm = w >> 1, wn = w & 1;
  const int i0 = blockIdx.x * 64;
  const int n0 = blockIdx.y * 64;

  f32x4 acc[2][2] = {};
  const int srow = t & 63, sseg = t >> 6;          // srow=lane, sseg=wave

  for (int kt = 0; kt < FIN / 64; ++kt) {
    const int k0 = kt * 64;
    // stage A: h f32 -> bf16 inline (16 floats/thread)
    {
      const float4* gA = (const float4*)(h + (size_t)(i0 + srow) * FIN + k0 + sseg * 16);
      float4 v0 = gA[0], v1 = gA[1], v2 = gA[2], v3 = gA[3];
      uint4 c0, c1;
      c0.x = pk2(v0.x, v0.y); c0.y = pk2(v0.z, v0.w);
      c0.z = pk2(v1.x, v1.y); c0.w = pk2(v1.z, v1.w);
      c1.x = pk2(v2.x, v2.y); c1.y = pk2(v2.z, v2.w);
      c1.z = pk2(v3.x, v3.y); c1.w = pk2(v3.z, v3.w);
      *(uint4*)&As[swz(srow, sseg * 2 + 0)] = c0;
      *(uint4*)&As[swz(srow, sseg * 2 + 1)] = c1;
    }
    // stage B: WT bf16 rows
    {
      const uint4* gB = (const uint4*)(WT + (size_t)(n0 + srow) * FIN + k0 + sseg * 16);
      uint4 b0 = gB[0], b1 = gB[1];
      *(uint4*)&Ws[swz(srow, sseg * 2 + 0)] = b0;
      *(uint4*)&Ws[swz(srow, sseg * 2 + 1)] = b1;
    }
    __syncthreads();
#pragma unroll
    for (int kk = 0; kk < 2; ++kk) {
      const int kc = kk * 4 + (lane >> 4);
      bf16x8 af[2], bfv[2];
#pragma unroll
      for (int fi = 0; fi < 2; ++fi)
        af[fi] = *(const bf16x8*)&As[swz(wm * 32 + fi * 16 + (lane & 15), kc)];
#pragma unroll
      for (int fj = 0; fj < 2; ++fj)
        bfv[fj] = *(const bf16x8*)&Ws[swz(wn * 32 + fj * 16 + (lane & 15), kc)];
#pragma unroll
      for (int fi = 0; fi < 2; ++fi)
#pragma unroll
        for (int fj = 0; fj < 2; ++fj)
          acc[fi][fj] = __builtin_amdgcn_mfma_f32_16x16x32_bf16(af[fi], bfv[fj], acc[fi][fj], 0, 0, 0);
    }
    __syncthreads();
  }

  // epilogue: store WhT (bf16, transposed) + per-row f1/f2 partials from ROUNDED Wh
  float p1[2][4] = {}, p2[2][4] = {};
#pragma unroll
  for (int fi = 0; fi < 2; ++fi) {
    const int row0 = i0 + wm * 32 + fi * 16 + ((lane >> 4) << 2);
#pragma unroll
    for (int fj = 0; fj < 2; ++fj) {
      const int col = n0 + wn * 32 + fj * 16 + (lane & 15);
      const float a1c = a[col], a2c = a[FOUT + col];
      ushort ov[4];
      ushort4 o;
#pragma unroll
      for (int rr = 0; rr < 4; ++rr) {
        ov[rr] = f2b(acc[fi][fj][rr]);
        float v = b2f(ov[rr]);
        p1[fi][rr] = fmaf(v, a1c, p1[fi][rr]);
        p2[fi][rr] = fmaf(v, a2c, p2[fi][rr]);
      }
      o.x = ov[0]; o.y = ov[1]; o.z = ov[2]; o.w = ov[3];
      *(ushort4*)&WhT[(size_t)col * NV + row0] = o;
    }
  }
#pragma unroll
  for (int fi = 0; fi < 2; ++fi)
#pragma unroll
    for (int rr = 0; rr < 4; ++rr) {
      float s1 = p1[fi][rr], s2 = p2[fi][rr];
#pragma unroll
      for (int m = 1; m < 16; m <<= 1) {
        s1 += __shfl_xor(s1, m);
        s2 += __shfl_xor(s2, m);
      }
      if ((lane & 15) == 0) {
        const int row = i0 + wm * 32 + fi * 16 + ((lane >> 4) << 2) + rr;
        atomicAdd(&f1[row], s1);
        atomicAdd(&f2[row], s2);
      }
    }
}

// ---------------- kernel 2: global max of f2 ----------------
__global__ void k_fmax(const float* __restrict__ f2, float* __restrict__ mfp) {
  __shared__ float red[16];
  const int tid = threadIdx.x;                     // 1024
  float m = -3e38f;
  for (int i = tid; i < NV; i += 1024) m = fmaxf(m, f2[i]);
#pragma unroll
  for (int off = 32; off > 0; off >>= 1) m = fmaxf(m, __shfl_xor(m, off));
  if ((tid & 63) == 0) red[tid >> 6] = m;
  __syncthreads();
  if (tid < 64) {
    float v = (tid < 16) ? red[tid] : -3e38f;
#pragma unroll
    for (int off = 8; off > 0; off >>= 1) v = fmaxf(v, __shfl_xor(v, off));
    if (tid == 0) mfp[0] = v;
  }
}

// ---------------- kernel 3: fused mask/exp/PV partial GEMM ----------------
// BM=64, BN=256 (full), K-split=4; 512 thr (8 waves, 2x4); grid 512 (2 blocks/CU)
// adj: 2-tile-deep register prefetch (reg loads survive __syncthreads);
// Bs: 1-ahead global_load_lds double-buffer; Ps: dbuf, exp after MFMA.
__global__ __launch_bounds__(512, 4) void k_gemm2(
    const int* __restrict__ adj, const ushort* __restrict__ WhT,
    const float* __restrict__ f1, const float* __restrict__ f2,
    const float* __restrict__ mfp,
    float* __restrict__ accP, float* __restrict__ Sp) {
  __shared__ __align__(16) ushort Ps[2][64 * 64];     // 16 KB
  __shared__ __align__(16) ushort Bs[2][256 * 64];    // 64 KB

  const int t = threadIdx.x;
  const int lane = t & 63;
  const int w = t >> 6;
  const int wm = w >> 2, wn = w & 3;
  const int bid = blockIdx.x;
  const int ks = bid & (KS - 1);
  const int rb = bid >> 2;
  const int i0 = rb * 64;
  const int jbase = ks * (NV / KS);
  const int NT = (NV / KS) / 64;                       // 32 k-tiles

  const int pr = t >> 3, pq = t & 7;                   // P role: row, 8-col chunk
  const float mf = mfp[0];
  const float f1r = f1[i0 + pr];
  const float e0 = f1r + mf;
  const float cr = fmaxf(e0, ALPHA_LRELU * e0);        // c_i >= row max of e

  const int lrow = lane >> 3;
  const int lchunk = (lane & 7) ^ lrow;                // pre-swizzled source chunk
  const ushort* wsrc0 = WhT + (size_t)(w * 32 + lrow) * NV + jbase + lchunk * 8;
  const int* adjp = adj + (size_t)(i0 + pr) * NV + jbase + pq * 8;
  const float* f2p = f2 + jbase + pq * 8;

  float ssum = 0.f;
  f32x4 acc[2][4] = {};
  int avA[8], avB[8];
  float fz[8];

  auto adjload = [&](int tile, int (&av)[8]) {
    int4 a0 = *(const int4*)(adjp + tile * 64);
    int4 a1 = *(const int4*)(adjp + tile * 64 + 4);
    av[0] = a0.x; av[1] = a0.y; av[2] = a0.z; av[3] = a0.w;
    av[4] = a1.x; av[5] = a1.y; av[6] = a1.z; av[7] = a1.w;
  };
  auto fzload = [&](int tile) {
    float4 z0 = *(const float4*)(f2p + tile * 64);
    float4 z1 = *(const float4*)(f2p + tile * 64 + 4);
    fz[0] = z0.x; fz[1] = z0.y; fz[2] = z0.z; fz[3] = z0.w;
    fz[4] = z1.x; fz[5] = z1.y; fz[6] = z1.z; fz[7] = z1.w;
  };
  auto glB = [&](int tile, int buf) {
    const int koff = tile * 64;
#pragma unroll
    for (int q = 0; q < 4; ++q)
      gl_lds16(wsrc0 + (size_t)q * 8 * NV + koff, &Bs[buf][(w * 4 + q) * 512]);
  };
  auto finish = [&](const int (&av)[8], int buf) {
    ushort ub[8];
#pragma unroll
    for (int e = 0; e < 8; ++e) {
      float x = f1r + fz[e];
      float ee = fmaxf(x, ALPHA_LRELU * x) - cr;
      float wv = (av[e] > 0) ? __expf(ee) : 0.f;
      ub[e] = f2b(wv);
      ssum += b2f(ub[e]);
    }
    uint4 pk;
    pk.x = (uint32_t)ub[0] | ((uint32_t)ub[1] << 16);
    pk.y = (uint32_t)ub[2] | ((uint32_t)ub[3] << 16);
    pk.z = (uint32_t)ub[4] | ((uint32_t)ub[5] << 16);
    pk.w = (uint32_t)ub[6] | ((uint32_t)ub[7] << 16);
    *(uint4*)&Ps[buf][swz(pr, pq)] = pk;
  };
  auto mfma_step = [&](int buf) {
#pragma unroll
    for (int kk = 0; kk < 2; ++kk) {
      const int kc = kk * 4 + (lane >> 4);
      bf16x8 af[2], bfv[4];
#pragma unroll
      for (int fi = 0; fi < 2; ++fi)
        af[fi] = *(const bf16x8*)&Ps[buf][swz(wm * 32 + fi * 16 + (lane & 15), kc)];
#pragma unroll
      for (int fj = 0; fj < 4; ++fj)
        bfv[fj] = *(const bf16x8*)&Bs[buf][swz(wn * 64 + fj * 16 + (lane & 15), kc)];
#pragma unroll
      for (int fi = 0; fi < 2; ++fi)
#pragma unroll
        for (int fj = 0; fj < 4; ++fj)
          acc[fi][fj] = __builtin_amdgcn_mfma_f32_16x16x32_bf16(af[fi], bfv[fj], acc[fi][fj], 0, 0, 0);
    }
  };

  // prologue: tile0 -> Ps[0]; tile1 adj in flight (set B)
  adjload(0, avA);
  adjload(1, avB);
  glB(0, 0);
  fzload(0);
  finish(avA, 0);
  __syncthreads();

  for (int kt = 0; kt < NT; kt += 2) {
    // even: compute tile kt (buf0); prefetch Bs kt+1, adj kt+2; finish kt+1 -> Ps[1]
    glB(kt + 1, 1);
    if (kt + 2 < NT) adjload(kt + 2, avA);
    fzload(kt + 1);
    mfma_step(0);
    finish(avB, 1);
    __syncthreads();
    // odd: compute tile kt+1 (buf1); prefetch Bs kt+2, adj kt+3; finish kt+2 -> Ps[0]
    if (kt + 2 < NT) {
      glB(kt + 2, 0);
      if (kt + 3 < NT) adjload(kt + 3, avB);
      fzload(kt + 2);
    }
    mfma_step(1);
    if (kt + 2 < NT) finish(avA, 0);
    __syncthreads();
  }

  // denom partial: reduce over the 8 chunk-lanes of each row
  ssum += __shfl_xor(ssum, 1);
  ssum += __shfl_xor(ssum, 2);
  ssum += __shfl_xor(ssum, 4);
  if (pq == 0) Sp[(size_t)ks * NV + i0 + pr] = ssum;

  float* ab = accP + (size_t)ks * NV * FOUT;
#pragma unroll
  for (int fi = 0; fi < 2; ++fi) {
    const int ig = i0 + wm * 32 + fi * 16 + ((lane >> 4) << 2);
#pragma unroll
    for (int fj = 0; fj < 4; ++fj) {
      const int col = wn * 64 + fj * 16 + (lane & 15);
#pragma unroll
      for (int rr = 0; rr < 4; ++rr)
        ab[(size_t)(ig + rr) * FOUT + col] = acc[fi][fj][rr];
    }
  }
}

// ---------------- kernel 4: combine partials, divide, ELU, f32 out ----------------
__global__ void k_combine(const float* __restrict__ accP, const float* __restrict__ Sp,
                          float* __restrict__ out) {
  const size_t NF = (size_t)NV * FOUT;
  int g = blockIdx.x * 256 + threadIdx.x;
  int i = g >> 6;
  float4 v0 = ((const float4*)accP)[g];
  float4 v1 = ((const float4*)(accP + NF))[g];
  float4 v2 = ((const float4*)(accP + 2 * NF))[g];
  float4 v3 = ((const float4*)(accP + 3 * NF))[g];
  float s = Sp[i] + Sp[NV + i] + Sp[2 * NV + i] + Sp[3 * NV + i];
  float inv = (s != 0.f) ? (1.0f / s) : 0.f;
  float xs0 = (v0.x + v1.x + v2.x + v3.x) * inv;
  float xs1 = (v0.y + v1.y + v2.y + v3.y) * inv;
  float xs2 = (v0.z + v1.z + v2.z + v3.z) * inv;
  float xs3 = (v0.w + v1.w + v2.w + v3.w) * inv;
  float4 o;
  o.x = xs0 > 0.f ? xs0 : expm1f(xs0);
  o.y = xs1 > 0.f ? xs1 : expm1f(xs1);
  o.z = xs2 > 0.f ? xs2 : expm1f(xs2);
  o.w = xs3 > 0.f ? xs3 : expm1f(xs3);
  ((float4*)out)[g] = o;
}

extern "C" void kernel_launch(void* const* d_in, const int* in_sizes, int n_in,
                              void* d_out, int out_size, void* d_ws, size_t ws_size,
                              hipStream_t stream) {
  const float* h   = (const float*)d_in[0];        // f32 [8192][512]
  const int*   adj = (const int*)d_in[1];          // int32 [8192][8192]
  const float* W   = (const float*)d_in[2];        // f32 [512][256]
  const float* a   = (const float*)d_in[3];        // f32 [512]
  float* out = (float*)d_out;                      // f32 [8192][256]

  char* ws = (char*)d_ws;
  ushort* WT   = (ushort*)ws;                                   // 256 KB
  ushort* WhT  = (ushort*)(ws + (256ull << 10));                // 4 MB
  float*  f1   = (float*)(ws + (256ull << 10) + (4ull << 20));
  float*  f2   = f1 + NV;
  float*  mfp  = f2 + NV;                                       // 1 float (pad 64)
  float*  Sp   = mfp + 64;                                      // 4*8192 floats
  float*  accP = Sp + (size_t)KS * NV;                          // 32 MB

  hipMemsetAsync(f1, 0, 2 * NV * sizeof(float), stream);        // f1+f2 contiguous
  k_prep_w<<<(FIN * FOUT) / 256, 256, 0, stream>>>(W, WT);
  k_gemm1<<<dim3(NV / 64, FOUT / 64), 256, 0, stream>>>(h, WT, a, WhT, f1, f2);
  k_fmax<<<1, 1024, 0, stream>>>(f2, mfp);
  k_gemm2<<<(NV / 64) * KS, 512, 0, stream>>>(adj, WhT, f1, f2, mfp, accP, Sp);
  k_combine<<<(NV * FOUT / 4) / 256, 256, 0, stream>>>(accP, Sp, out);
}

// Round 6
// 412.202 us; speedup vs baseline: 1.1059x; 1.0447x over previous
//
#include <hip/hip_runtime.h>
#include <hip/hip_bf16.h>
#include <cstdint>

#define NV 8192
#define FIN 512
#define FOUT 256
#define KS 4
#define ALPHA_LRELU 0.2f

using bf16x8 = __attribute__((ext_vector_type(8))) short;
using f32x4  = __attribute__((ext_vector_type(4))) float;

static __device__ __forceinline__ float b2f(ushort u) {
  union { uint32_t u32; float f; } v; v.u32 = ((uint32_t)u) << 16; return v.f;
}
static __device__ __forceinline__ ushort f2b(float f) {
  union { float f; uint32_t u; } v; v.f = f;
  uint32_t r = (v.u + 0x7fffu + ((v.u >> 16) & 1u)) >> 16;
  return (ushort)r;
}
static __device__ __forceinline__ uint32_t pk2(float a, float b) {
  return (uint32_t)f2b(a) | ((uint32_t)f2b(b) << 16);
}
// swizzled element index of an 8-elem (16B) chunk; tile row stride 64 elems (128B)
static __device__ __forceinline__ int swz(int row, int kchunk) {
  return (row << 6) + (((kchunk ^ (row & 7)) & 7) << 3);
}
// direct global->LDS, 16B per lane (dest = wave-uniform base + lane*16)
static __device__ __forceinline__ void gl_lds16(const ushort* g, ushort* l) {
  __builtin_amdgcn_global_load_lds(
      (const __attribute__((address_space(1))) uint32_t*)(uintptr_t)g,
      (__attribute__((address_space(3))) uint32_t*)(uint32_t)(uintptr_t)l,
      16, 0, 0);
}

// ---------------- prep: W f32 -> WT bf16 (transposed) + zero f1/f2 ----------------
__global__ void k_prep_w(const float* __restrict__ W, ushort* __restrict__ WT,
                         float* __restrict__ f1z) {
  int t = blockIdx.x * 256 + threadIdx.x;
  int n = t >> 9, k = t & 511;
  WT[(size_t)n * FIN + k] = f2b(W[(size_t)k * FOUT + n]);
  if (t < 2 * NV) f1z[t] = 0.f;          // f1 and f2 are contiguous
}

// ---------------- kernel 1: WhT[c][i] = (h@W)^T bf16, + f1/f2 partials ----------------
__global__ __launch_bounds__(256, 4) void k_gemm1(
    const float* __restrict__ h, const ushort* __restrict__ WT,
    const float* __restrict__ a,
    ushort* __restrict__ WhT, float* __restrict__ f1, float* __restrict__ f2) {
  __shared__ __align__(16) ushort As[64 * 64];
  __shared__ __align__(16) ushort Ws[64 * 64];
  const int t = threadIdx.x;
  const int lane = t & 63;
  const int w = t >> 6;
  const int wm = w >> 1, wn = w & 1;
  const int i0 = blockIdx.x * 64;
  const int n0 = blockIdx.y * 64;

  f32x4 acc[2][2] = {};
  const int srow = t & 63, sseg = t >> 6;

  for (int kt = 0; kt < FIN / 64; ++kt) {
    const int k0 = kt * 64;
    {
      const float4* gA = (const float4*)(h + (size_t)(i0 + srow) * FIN + k0 + sseg * 16);
      float4 v0 = gA[0], v1 = gA[1], v2 = gA[2], v3 = gA[3];
      uint4 c0, c1;
      c0.x = pk2(v0.x, v0.y); c0.y = pk2(v0.z, v0.w);
      c0.z = pk2(v1.x, v1.y); c0.w = pk2(v1.z, v1.w);
      c1.x = pk2(v2.x, v2.y); c1.y = pk2(v2.z, v2.w);
      c1.z = pk2(v3.x, v3.y); c1.w = pk2(v3.z, v3.w);
      *(uint4*)&As[swz(srow, sseg * 2 + 0)] = c0;
      *(uint4*)&As[swz(srow, sseg * 2 + 1)] = c1;
    }
    {
      const uint4* gB = (const uint4*)(WT + (size_t)(n0 + srow) * FIN + k0 + sseg * 16);
      uint4 b0 = gB[0], b1 = gB[1];
      *(uint4*)&Ws[swz(srow, sseg * 2 + 0)] = b0;
      *(uint4*)&Ws[swz(srow, sseg * 2 + 1)] = b1;
    }
    __syncthreads();
#pragma unroll
    for (int kk = 0; kk < 2; ++kk) {
      const int kc = kk * 4 + (lane >> 4);
      bf16x8 af[2], bfv[2];
#pragma unroll
      for (int fi = 0; fi < 2; ++fi)
        af[fi] = *(const bf16x8*)&As[swz(wm * 32 + fi * 16 + (lane & 15), kc)];
#pragma unroll
      for (int fj = 0; fj < 2; ++fj)
        bfv[fj] = *(const bf16x8*)&Ws[swz(wn * 32 + fj * 16 + (lane & 15), kc)];
#pragma unroll
      for (int fi = 0; fi < 2; ++fi)
#pragma unroll
        for (int fj = 0; fj < 2; ++fj)
          acc[fi][fj] = __builtin_amdgcn_mfma_f32_16x16x32_bf16(af[fi], bfv[fj], acc[fi][fj], 0, 0, 0);
    }
    __syncthreads();
  }

  float p1[2][4] = {}, p2[2][4] = {};
#pragma unroll
  for (int fi = 0; fi < 2; ++fi) {
    const int row0 = i0 + wm * 32 + fi * 16 + ((lane >> 4) << 2);
#pragma unroll
    for (int fj = 0; fj < 2; ++fj) {
      const int col = n0 + wn * 32 + fj * 16 + (lane & 15);
      const float a1c = a[col], a2c = a[FOUT + col];
      ushort ov[4];
      ushort4 o;
#pragma unroll
      for (int rr = 0; rr < 4; ++rr) {
        ov[rr] = f2b(acc[fi][fj][rr]);
        float v = b2f(ov[rr]);
        p1[fi][rr] = fmaf(v, a1c, p1[fi][rr]);
        p2[fi][rr] = fmaf(v, a2c, p2[fi][rr]);
      }
      o.x = ov[0]; o.y = ov[1]; o.z = ov[2]; o.w = ov[3];
      *(ushort4*)&WhT[(size_t)col * NV + row0] = o;
    }
  }
#pragma unroll
  for (int fi = 0; fi < 2; ++fi)
#pragma unroll
    for (int rr = 0; rr < 4; ++rr) {
      float s1 = p1[fi][rr], s2 = p2[fi][rr];
#pragma unroll
      for (int m = 1; m < 16; m <<= 1) {
        s1 += __shfl_xor(s1, m);
        s2 += __shfl_xor(s2, m);
      }
      if ((lane & 15) == 0) {
        const int row = i0 + wm * 32 + fi * 16 + ((lane >> 4) << 2) + rr;
        atomicAdd(&f1[row], s1);
        atomicAdd(&f2[row], s2);
      }
    }
}

// ---------------- kernel 2: fused mask/exp/PV partial GEMM ----------------
// BM=64, BN=256 (full), K-split=4; 512 thr (8 waves, 2x4); grid 512 (2 blk/CU)
// adj/f2: 2-phase-deep named register sets; Bs/Ps double-buffered;
// all of a phase's loads issue before its MFMA cluster; one __syncthreads/phase.
__global__ __launch_bounds__(512, 4) void k_gemm2(
    const int* __restrict__ adj, const ushort* __restrict__ WhT,
    const float* __restrict__ f1, const float* __restrict__ f2,
    float* __restrict__ accP, float* __restrict__ Sp) {
  __shared__ __align__(16) ushort Ps[2][64 * 64];     // 16 KB
  __shared__ __align__(16) ushort Bs[2][256 * 64];    // 64 KB  (80 KB -> 2 blk/CU)

  const int t = threadIdx.x;
  const int lane = t & 63;
  const int w = t >> 6;
  const int wm = w >> 2, wn = w & 3;
  const int bid = blockIdx.x;
  const int ks = bid & (KS - 1);
  const int rb = bid >> 2;
  const int i0 = rb * 64;
  const int jbase = ks * (NV / KS);
  const int NT = (NV / KS) / 64;                       // 32 k-tiles

  const int pr = t >> 3, pq = t & 7;                   // P role: row, 8-col chunk
  const float f1r = f1[i0 + pr];

  const int lrow = lane >> 3;
  const int lchunk = (lane & 7) ^ lrow;                // pre-swizzled source chunk
  const ushort* wsrc0 = WhT + (size_t)(w * 32 + lrow) * NV + jbase + lchunk * 8;
  const int* adjp = adj + (size_t)(i0 + pr) * NV + jbase + pq * 8;
  const float* f2p = f2 + jbase + pq * 8;

  float ssum = 0.f;
  f32x4 acc[2][4] = {};
  int avA[8], avB[8];
  float fzA[8], fzB[8];

  auto adjload = [&](int tile, int (&av)[8]) {
    int4 a0 = *(const int4*)(adjp + tile * 64);
    int4 a1 = *(const int4*)(adjp + tile * 64 + 4);
    av[0] = a0.x; av[1] = a0.y; av[2] = a0.z; av[3] = a0.w;
    av[4] = a1.x; av[5] = a1.y; av[6] = a1.z; av[7] = a1.w;
  };
  auto fzload = [&](int tile, float (&fz)[8]) {
    float4 z0 = *(const float4*)(f2p + tile * 64);
    float4 z1 = *(const float4*)(f2p + tile * 64 + 4);
    fz[0] = z0.x; fz[1] = z0.y; fz[2] = z0.z; fz[3] = z0.w;
    fz[4] = z1.x; fz[5] = z1.y; fz[6] = z1.z; fz[7] = z1.w;
  };
  auto glB = [&](int tile, int buf) {
    const int koff = tile * 64;
#pragma unroll
    for (int q = 0; q < 4; ++q)
      gl_lds16(wsrc0 + (size_t)q * 8 * NV + koff, &Bs[buf][(w * 4 + q) * 512]);
  };
  auto finish = [&](const int (&av)[8], const float (&fz)[8], int buf) {
    ushort ub[8];
#pragma unroll
    for (int e = 0; e < 8; ++e) {
      float x = f1r + fz[e];
      float ee = fminf(fmaxf(x, ALPHA_LRELU * x), 75.f);   // lrelu + overflow guard
      float wv = (av[e] > 0) ? __expf(ee) : 0.f;
      ub[e] = f2b(wv);
      ssum += b2f(ub[e]);
    }
    uint4 pk;
    pk.x = (uint32_t)ub[0] | ((uint32_t)ub[1] << 16);
    pk.y = (uint32_t)ub[2] | ((uint32_t)ub[3] << 16);
    pk.z = (uint32_t)ub[4] | ((uint32_t)ub[5] << 16);
    pk.w = (uint32_t)ub[6] | ((uint32_t)ub[7] << 16);
    *(uint4*)&Ps[buf][swz(pr, pq)] = pk;
  };
  auto mfma_step = [&](int buf) {
#pragma unroll
    for (int kk = 0; kk < 2; ++kk) {
      const int kc = kk * 4 + (lane >> 4);
      bf16x8 af[2], bfv[4];
#pragma unroll
      for (int fi = 0; fi < 2; ++fi)
        af[fi] = *(const bf16x8*)&Ps[buf][swz(wm * 32 + fi * 16 + (lane & 15), kc)];
#pragma unroll
      for (int fj = 0; fj < 4; ++fj)
        bfv[fj] = *(const bf16x8*)&Bs[buf][swz(wn * 64 + fj * 16 + (lane & 15), kc)];
#pragma unroll
      for (int fi = 0; fi < 2; ++fi)
#pragma unroll
        for (int fj = 0; fj < 4; ++fj)
          acc[fi][fj] = __builtin_amdgcn_mfma_f32_16x16x32_bf16(af[fi], bfv[fj], acc[fi][fj], 0, 0, 0);
    }
  };

  // ---- prologue: tile0 staged; tile1 adj/f2 in named regs ----
  adjload(0, avA); fzload(0, fzA);
  glB(0, 0);
  adjload(1, avB); fzload(1, fzB);
  finish(avA, fzA, 0);                  // waits only on set A
  __syncthreads();

  // ---- main loop: two phases per iteration; kt = 0,2,..,NT-4 ----
  for (int kt = 0; kt + 2 < NT; kt += 2) {
    // even phase (cur=0): loads first, then compute; finish uses LAST phase's set B
    glB(kt + 1, 1);
    adjload(kt + 2, avA); fzload(kt + 2, fzA);
    mfma_step(0);
    finish(avB, fzB, 1);
    __syncthreads();
    // odd phase (cur=1)
    glB(kt + 2, 0);
    adjload(kt + 3, avB); fzload(kt + 3, fzB);
    mfma_step(1);
    finish(avA, fzA, 0);
    __syncthreads();
  }

  // ---- tail: phase NT-2 (cur=0) ----
  glB(NT - 1, 1);
  mfma_step(0);
  finish(avB, fzB, 1);
  __syncthreads();
  // ---- tail: phase NT-1 (cur=1), compute only ----
  mfma_step(1);

  // denom partial: reduce over the 8 chunk-lanes of each row
  ssum += __shfl_xor(ssum, 1);
  ssum += __shfl_xor(ssum, 2);
  ssum += __shfl_xor(ssum, 4);
  if (pq == 0) Sp[(size_t)ks * NV + i0 + pr] = ssum;

  float* ab = accP + (size_t)ks * NV * FOUT;
#pragma unroll
  for (int fi = 0; fi < 2; ++fi) {
    const int ig = i0 + wm * 32 + fi * 16 + ((lane >> 4) << 2);
#pragma unroll
    for (int fj = 0; fj < 4; ++fj) {
      const int col = wn * 64 + fj * 16 + (lane & 15);
#pragma unroll
      for (int rr = 0; rr < 4; ++rr)
        ab[(size_t)(ig + rr) * FOUT + col] = acc[fi][fj][rr];
    }
  }
}

// ---------------- kernel 3: combine partials, divide, ELU, f32 out ----------------
__global__ void k_combine(const float* __restrict__ accP, const float* __restrict__ Sp,
                          float* __restrict__ out) {
  const size_t NF = (size_t)NV * FOUT;
  int g = blockIdx.x * 256 + threadIdx.x;
  int i = g >> 6;
  float4 v0 = ((const float4*)accP)[g];
  float4 v1 = ((const float4*)(accP + NF))[g];
  float4 v2 = ((const float4*)(accP + 2 * NF))[g];
  float4 v3 = ((const float4*)(accP + 3 * NF))[g];
  float s = Sp[i] + Sp[NV + i] + Sp[2 * NV + i] + Sp[3 * NV + i];
  float inv = (s != 0.f) ? (1.0f / s) : 0.f;
  float xs0 = (v0.x + v1.x + v2.x + v3.x) * inv;
  float xs1 = (v0.y + v1.y + v2.y + v3.y) * inv;
  float xs2 = (v0.z + v1.z + v2.z + v3.z) * inv;
  float xs3 = (v0.w + v1.w + v2.w + v3.w) * inv;
  float4 o;
  o.x = xs0 > 0.f ? xs0 : expm1f(xs0);
  o.y = xs1 > 0.f ? xs1 : expm1f(xs1);
  o.z = xs2 > 0.f ? xs2 : expm1f(xs2);
  o.w = xs3 > 0.f ? xs3 : expm1f(xs3);
  ((float4*)out)[g] = o;
}

extern "C" void kernel_launch(void* const* d_in, const int* in_sizes, int n_in,
                              void* d_out, int out_size, void* d_ws, size_t ws_size,
                              hipStream_t stream) {
  const float* h   = (const float*)d_in[0];        // f32 [8192][512]
  const int*   adj = (const int*)d_in[1];          // int32 [8192][8192]
  const float* W   = (const float*)d_in[2];        // f32 [512][256]
  const float* a   = (const float*)d_in[3];        // f32 [512]
  float* out = (float*)d_out;                      // f32 [8192][256]

  char* ws = (char*)d_ws;
  ushort* WT   = (ushort*)ws;                                   // 256 KB
  ushort* WhT  = (ushort*)(ws + (256ull << 10));                // 4 MB
  float*  f1   = (float*)(ws + (256ull << 10) + (4ull << 20));  // f1,f2 contiguous
  float*  f2   = f1 + NV;
  float*  Sp   = f2 + NV;                                       // 4*8192 floats
  float*  accP = Sp + (size_t)KS * NV;                          // 32 MB

  k_prep_w<<<(FIN * FOUT) / 256, 256, 0, stream>>>(W, WT, f1);
  k_gemm1<<<dim3(NV / 64, FOUT / 64), 256, 0, stream>>>(h, WT, a, WhT, f1, f2);
  k_gemm2<<<(NV / 64) * KS, 512, 0, stream>>>(adj, WhT, f1, f2, accP, Sp);
  k_combine<<<(NV * FOUT / 4) / 256, 256, 0, stream>>>(accP, Sp, out);
}